// Round 12
// baseline (4044.131 us; speedup 1.0000x reference)
//
#include <hip/hip_runtime.h>

#define BB 512
#define LL 2000
#define DD 16
#define HH 128
#define WD 256
#define NLBL 10
#define NSTEPS 500
#define G 16
#define NSL 8             // h-slices per batch-group
#define NGRP (BB / G)     // 32 groups
#define NWG (NGRP * NSL)  // 256 workgroups (1 per CU)
#define NTHR 512
#define X8S 35            // X8w row stride in u64 (bank-conflict fix)

typedef __bf16 bf16x8 __attribute__((ext_vector_type(8)));
typedef float f32x4 __attribute__((ext_vector_type(4)));

__device__ __forceinline__ float aload(const float* p) {
  return __hip_atomic_load(p, __ATOMIC_RELAXED, __HIP_MEMORY_SCOPE_AGENT);
}
__device__ __forceinline__ void astore(float* p, float v) {
  __hip_atomic_store(p, v, __ATOMIC_RELAXED, __HIP_MEMORY_SCOPE_AGENT);
}
__device__ __forceinline__ unsigned int aloadu(const unsigned int* p) {
  return __hip_atomic_load(p, __ATOMIC_RELAXED, __HIP_MEMORY_SCOPE_AGENT);
}
__device__ __forceinline__ void astoreu(unsigned int* p, unsigned int v) {
  __hip_atomic_store(p, v, __ATOMIC_RELAXED, __HIP_MEMORY_SCOPE_AGENT);
}

__device__ __forceinline__ unsigned short f2bf(float f) {
  unsigned int u = __float_as_uint(f);
  u += 0x7FFFu + ((u >> 16) & 1u);
  return (unsigned short)(u >> 16);
}
__device__ __forceinline__ unsigned int pk2bf(float a, float b) {
  return (unsigned int)f2bf(a) | ((unsigned int)f2bf(b) << 16);
}

// XOR-swizzled element offset into a [rows][256] bf16 LDS tile (16B chunks)
__device__ __forceinline__ int swz(int r, int c) {
  return r * WD + ((((c >> 3) ^ (r & 7)) << 3) | (c & 7));
}

__device__ __forceinline__ bf16x8 ldfrag(const unsigned short* buf, int row, int chunk) {
  return *reinterpret_cast<const bf16x8*>(buf + row * WD + ((chunk ^ (row & 7)) << 3));
}

// OCP e4m3fn encode, RNE (prep only)
__device__ unsigned char enc_e4m3(float x) {
  float ax = fabsf(x);
  unsigned char sg = (unsigned char)((__float_as_uint(x) >> 24) & 0x80u);
  if (ax > 448.f) ax = 448.f;
  if (ax < 0.001953125f) {
    int m = (int)rintf(ax * 512.f);
    return sg | (unsigned char)m;
  }
  unsigned int u = __float_as_uint(ax);
  unsigned int r = u + 0x7FFFFu + ((u >> 20) & 1u);
  r &= 0xFFF00000u;
  int e = (int)(r >> 23) - 127;
  if (e < -6) {
    int m = (int)rintf(ax * 512.f);
    if (m >= 8) return sg | 0x08;
    return sg | (unsigned char)m;
  }
  if (e > 8) return sg | 0x7E;
  unsigned int m = (r >> 20) & 7u;
  return sg | (unsigned char)(((e + 7) << 3) | m);
}

// pack 4 f32 -> 4 fp8 e4m3 bytes in one uint
__device__ __forceinline__ unsigned int pk4_fp8(float a, float b, float c, float d) {
#if __has_builtin(__builtin_amdgcn_cvt_pk_fp8_f32)
  int w0 = __builtin_amdgcn_cvt_pk_fp8_f32(a, b, 0, false);
  w0 = __builtin_amdgcn_cvt_pk_fp8_f32(c, d, w0, true);
  return (unsigned int)w0;
#else
  return (unsigned int)enc_e4m3(a) | ((unsigned int)enc_e4m3(b) << 8) |
         ((unsigned int)enc_e4m3(c) << 16) | ((unsigned int)enc_e4m3(d) << 24);
#endif
}

struct __align__(16) SM {
  uint2 q8l[16 * 512];                 // 64KB: slice W3 fp8, frag-major (16 h-tiles)
  float Y[G][HH];                      // 8K
  float K1[G][HH];                     // 8K (full, from exchange)
  unsigned short X[G * WD];            // 8K swizzled bf16 activations
  unsigned short Hb[G * WD];           // 8K swizzled bf16 H1
  unsigned long long X8w[G * X8S];     // H2 fp8 packed, 280B/row (bank fix)
  float dx[2][G][DD];                  // [stage][row][d]
  float b1[WD], b2[WD];
  float2 sb3[256];                     // {w3 row scale, b3} for owned slice
  float tsl[LL];
  float tau_tab[2 * NSTEPS];
  unsigned short idx_tab[2 * NSTEPS];
  float logits[G * NLBL];
};

// per-row absmax -> scale = max/240
__global__ void prep_scale(const float* __restrict__ W3, float* __restrict__ w3s) {
  int row = blockIdx.x * 4 + (threadIdx.x >> 6);
  int lane = threadIdx.x & 63;
  const float* wr = W3 + (size_t)row * WD;
  float m = 0.f;
#pragma unroll
  for (int i = 0; i < 4; ++i) m = fmaxf(m, fabsf(wr[lane + 64 * i]));
#pragma unroll
  for (int off = 32; off >= 1; off >>= 1) m = fmaxf(m, __shfl_xor(m, off));
  if (lane == 0) w3s[row] = fmaxf(m, 1e-30f) * (1.0f / 240.0f);
}

// pack W3 into frag-major fp8: uint2 index o = nt*512 + s*64 + lane
// holds bytes k = s*32 + (lane>>4)*8 + j of W3 row nt*16 + (lane&15)
__global__ void prep_pack(const float* __restrict__ W3, const float* __restrict__ w3s,
                          uint2* __restrict__ q8) {
  int o = blockIdx.x * blockDim.x + threadIdx.x;  // 65536
  int lane = o & 63, s = (o >> 6) & 7, nt = o >> 9;
  int row = nt * 16 + (lane & 15);
  int k0 = s * 32 + ((lane >> 4) << 3);
  float inv = 1.0f / w3s[row];
  const float* src = W3 + (size_t)row * WD + k0;
  unsigned int lo = 0, hi = 0;
#pragma unroll
  for (int j = 0; j < 4; ++j) lo |= (unsigned int)enc_e4m3(src[j] * inv) << (8 * j);
#pragma unroll
  for (int j = 0; j < 4; ++j) hi |= (unsigned int)enc_e4m3(src[4 + j] * inv) << (8 * j);
  q8[o] = make_uint2(lo, hi);
}

__global__ __launch_bounds__(NTHR, 2) void cde_main(
    const float* __restrict__ ts, const float* __restrict__ coeffs,
    const float* __restrict__ x0,
    const float* __restrict__ b1g, const float* __restrict__ b2g, const float* __restrict__ b3g,
    const float* __restrict__ Wl1, const float* __restrict__ bl1,
    const float* __restrict__ Wl2, const float* __restrict__ bl2,
    const float* __restrict__ W1, const float* __restrict__ W2,
    const uint2* __restrict__ q8g, const float* __restrict__ w3s,
    float* __restrict__ exA, float* __restrict__ exB,
    unsigned int* __restrict__ flags,
    float* __restrict__ out) {
  extern __shared__ char smraw[];
  SM& sm = *reinterpret_cast<SM*>(smraw);
  const int tid = threadIdx.x;
  const int bid = blockIdx.x;
  const int g = bid & 31, s16 = bid >> 5;  // group's 8 slices share bid%8 -> same XCD
  const int gb = g * G;
  const int w = tid >> 6, lane = tid & 63;
  const int row16 = lane & 15, kg = lane >> 4;

  const float ts0 = ts[0];
  const float dt = (ts[LL - 1] - ts0) / (float)NSTEPS;
  const float hdt = 0.5f * dt;

  // ---- prologue: LDS fills
  for (int i = tid; i < LL; i += NTHR) sm.tsl[i] = ts[i];
  for (int i = tid; i < WD; i += NTHR) { sm.b1[i] = b1g[i]; sm.b2[i] = b2g[i]; }
  for (int i = tid; i < 256; i += NTHR) {
    int rg = s16 * 256 + i;
    sm.sb3[i] = make_float2(w3s[rg], b3g[rg]);
  }
  for (int i = tid; i < 16 * 512; i += NTHR) sm.q8l[i] = q8g[s16 * 8192 + i];

  // y0 = x0 @ Wl1^T + bl1; stage X for k=0 stage-1
  for (int i = tid; i < G * HH; i += NTHR) {
    int r = i >> 7, h = i & (HH - 1);
    float s = bl1[h];
    const float* xr = x0 + (size_t)(gb + r) * DD;
    const float* wr = Wl1 + (size_t)h * DD;
#pragma unroll
    for (int d = 0; d < DD; ++d) s += xr[d] * wr[d];
    sm.Y[r][h] = s;
    sm.X[swz(r, h)] = f2bf(s);
  }

  // persistent W1/W2 fragments (lane&15 = weight-row index; dual-use A/B operand)
  bf16x8 w1f[2][4], w2f[2][8];
#pragma unroll
  for (int tt = 0; tt < 2; ++tt) {
    int n = (w + tt * 8) * 16 + row16;
#pragma unroll
    for (int s = 0; s < 4; ++s) {
      bf16x8 v;
#pragma unroll
      for (int e = 0; e < 8; ++e)
        v[e] = __builtin_bit_cast(__bf16, f2bf(W1[(size_t)n * HH + (s * 4 + kg) * 8 + e]));
      w1f[tt][s] = v;
    }
#pragma unroll
    for (int s = 0; s < 8; ++s) {
      bf16x8 v;
#pragma unroll
      for (int e = 0; e < 8; ++e)
        v[e] = __builtin_bit_cast(__bf16, f2bf(W2[(size_t)n * WD + (s * 4 + kg) * 8 + e]));
      w2f[tt][s] = v;
    }
  }
  __syncthreads();

  // idx/tau tables (bit-faithful to reference arithmetic)
  for (int e = tid; e < 2 * NSTEPS; e += NTHR) {
    int kk = e >> 1;
    float t = ts0 + (float)kk * dt;
    if (e & 1) t = t + dt;
    int lo = 0, hi = LL;
    while (lo < hi) { int m = (lo + hi) >> 1; if (sm.tsl[m] <= t) lo = m + 1; else hi = m; }
    int idx = lo - 1;
    if (idx < 0) idx = 0;
    if (idx > LL - 2) idx = LL - 2;
    sm.idx_tab[e] = (unsigned short)idx;
    sm.tau_tab[e] = t - sm.tsl[idx];
  }
  __syncthreads();

  // dx for step 0 (both stages)
  {
    int which = tid >> 8, rr = (tid >> 4) & 15, d = tid & 15;
    int idx = sm.idx_tab[which];
    float tau = sm.tau_tab[which];
    const float* cb = coeffs + ((size_t)(gb + rr) * 4 * (LL - 1) + idx) * DD + d;
    float c0 = cb[0];
    float c1 = cb[(size_t)(LL - 1) * DD];
    float c2 = cb[(size_t)2 * (LL - 1) * DD];
    sm.dx[which][rr][d] = c2 + 2.0f * tau * c1 + 3.0f * tau * tau * c0;
  }

  // ---- global init barrier (counter; one-time): done reading q8g (ex* alias it)
  {
    unsigned int* ic = &flags[8192];
    __syncthreads();
    if (tid == 0) {
      atomicAdd(ic, 1u);
      while (aloadu(ic) < NWG) __builtin_amdgcn_s_sleep(1);
    }
    __syncthreads();
  }

  float pc0 = 0.f, pc1 = 0.f, pc2 = 0.f, ptau = 0.f;  // next-step coeff prefetch
  unsigned int nb = 0;
  unsigned int* myflag = &flags[(g * 8 + s16) * 32];       // 128B-padded per-slice flag
  const unsigned int* peerflag = &flags[(g * 8 + (lane & 7)) * 32];

  // ---- one vf eval: B,C,D on staged X; K-slice -> exDst
  auto PH = [&](float* exDst, int stage) {
    // phase B (swapped): H1 = relu(X @ W1^T + b1); lane -> 4 consecutive h1, 1 batch
    {
      bf16x8 a[4];
#pragma unroll
      for (int s = 0; s < 4; ++s) a[s] = ldfrag(sm.X, row16, s * 4 + kg);
#pragma unroll
      for (int tt = 0; tt < 2; ++tt) {
        const int T = w + tt * 8;
        f32x4 acc = {0.f, 0.f, 0.f, 0.f};
#pragma unroll
        for (int s = 0; s < 4; ++s)
          acc = __builtin_amdgcn_mfma_f32_16x16x32_bf16(w1f[tt][s], a[s], acc, 0, 0, 0);
        const int h1b = T * 16 + kg * 4;
        const float4 b14 = *reinterpret_cast<const float4*>(&sm.b1[h1b]);
        float o0 = fmaxf(acc[0] + b14.x, 0.f);
        float o1 = fmaxf(acc[1] + b14.y, 0.f);
        float o2 = fmaxf(acc[2] + b14.z, 0.f);
        float o3 = fmaxf(acc[3] + b14.w, 0.f);
        // store 4 bf16 (elems h1b..h1b+3 of row row16) at swizzled chunk
        int cp = ((2 * T + (kg >> 1)) ^ (row16 & 7));
        uint2* dst = reinterpret_cast<uint2*>(sm.Hb + row16 * WD + cp * 8 + (kg & 1) * 4);
        *dst = make_uint2(pk2bf(o0, o1), pk2bf(o2, o3));
      }
    }
    __syncthreads();

    // phase C (swapped): H2 = relu(H1 @ W2^T + b2), packed fp8 -> X8w
    {
      bf16x8 hb[8];
#pragma unroll
      for (int s = 0; s < 8; ++s) hb[s] = ldfrag(sm.Hb, row16, s * 4 + kg);
      unsigned int* x8u = reinterpret_cast<unsigned int*>(sm.X8w);
#pragma unroll
      for (int tt = 0; tt < 2; ++tt) {
        const int T = w + tt * 8;
        f32x4 acc = {0.f, 0.f, 0.f, 0.f};
#pragma unroll
        for (int s = 0; s < 8; ++s)
          acc = __builtin_amdgcn_mfma_f32_16x16x32_bf16(w2f[tt][s], hb[s], acc, 0, 0, 0);
        const int nbi = T * 16 + kg * 4;
        const float4 b24 = *reinterpret_cast<const float4*>(&sm.b2[nbi]);
        float o0 = fmaxf(acc[0] + b24.x, 0.f);
        float o1 = fmaxf(acc[1] + b24.y, 0.f);
        float o2 = fmaxf(acc[2] + b24.z, 0.f);
        float o3 = fmaxf(acc[3] + b24.w, 0.f);
        x8u[row16 * (2 * X8S) + T * 4 + kg] = pk4_fp8(o0, o1, o2, o3);
      }
    }
    __syncthreads();

    // phase D: O = tanh(H2 @ W3^T + b3); K_slice = sum_d O*dX
    {
      long b8[8];
#pragma unroll
      for (int s = 0; s < 8; ++s)
        b8[s] = __builtin_bit_cast(long, sm.X8w[row16 * X8S + s * 4 + kg]);
      const float4 dx4 = *reinterpret_cast<const float4*>(&sm.dx[stage][row16][kg * 4]);
#pragma unroll
      for (int j = 0; j < 2; ++j) {
        const int ntl = w + j * 8;  // local h (0..15)
        const uint2* wp = sm.q8l + ntl * 512 + lane;
        f32x4 acc = {0.f, 0.f, 0.f, 0.f};
#pragma unroll
        for (int s = 0; s < 8; ++s)
          acc = __builtin_amdgcn_mfma_f32_16x16x32_fp8_fp8(
              __builtin_bit_cast(long, wp[s * 64]), b8[s], acc, 0, 0, 0);
        const float4* sb4 = reinterpret_cast<const float4*>(&sm.sb3[ntl * 16 + kg * 4]);
        float4 sba = sb4[0], sbb = sb4[1];
        float psum = 0.f;
        {
          float o = acc[0] * sba.x + sba.y;
          float e2 = __expf(2.0f * o);
          psum += (1.0f - 2.0f / (e2 + 1.0f)) * dx4.x;
          o = acc[1] * sba.z + sba.w;
          e2 = __expf(2.0f * o);
          psum += (1.0f - 2.0f / (e2 + 1.0f)) * dx4.y;
          o = acc[2] * sbb.x + sbb.y;
          e2 = __expf(2.0f * o);
          psum += (1.0f - 2.0f / (e2 + 1.0f)) * dx4.z;
          o = acc[3] * sbb.z + sbb.w;
          e2 = __expf(2.0f * o);
          psum += (1.0f - 2.0f / (e2 + 1.0f)) * dx4.w;
        }
        psum += __shfl_xor(psum, 16);
        psum += __shfl_xor(psum, 32);
        if (kg == 0) astore(exDst + (size_t)(gb + row16) * HH + (s16 * 16 + ntl), psum);
      }
    }
  };

  // arrive: syncthreads drains exchange stores; one plain flag store (no RMW)
  auto arrive = [&]() {
    __syncthreads();
    if (tid == 0) astoreu(myflag, nb);
  };
  // wait: wave 0 polls all 8 slice flags in parallel
  auto waitc = [&](unsigned int tgt) {
    if (w == 0) {
      bool done;
      do {
        bool ok = (lane >= 8) || (aloadu(peerflag) >= tgt);
        done = __all(ok);
        if (!done) __builtin_amdgcn_s_sleep(1);
      } while (!done);
    }
    __syncthreads();
  };

  for (int k = 0; k < NSTEPS; ++k) {
    // ---- stage 1 (X staged by prologue / previous consume1)
    {
      int which = tid >> 8, rr = (tid >> 4) & 15, d = tid & 15;
      int e = 2 * (k + 1) + which;
      if (e > 2 * NSTEPS - 1) e = 2 * NSTEPS - 1;
      int idx = sm.idx_tab[e];
      ptau = sm.tau_tab[e];
      const float* cb = coeffs + ((size_t)(gb + rr) * 4 * (LL - 1) + idx) * DD + d;
      pc0 = cb[0];
      pc1 = cb[(size_t)(LL - 1) * DD];
      pc2 = cb[(size_t)2 * (LL - 1) * DD];
    }
    PH(exA, 0);
    ++nb;
    arrive();
    waitc(nb);
    // consume0: K1 <- exA; stage X = f2bf(Y + dt*K1)
    {
      int r = tid >> 5, c = (tid & 31) << 2;
      const float* src = exA + (size_t)(gb + r) * HH + c;
      float f0 = aload(src), f1 = aload(src + 1), f2 = aload(src + 2), f3 = aload(src + 3);
      sm.K1[r][c] = f0; sm.K1[r][c + 1] = f1; sm.K1[r][c + 2] = f2; sm.K1[r][c + 3] = f3;
      sm.X[swz(r, c)] = f2bf(sm.Y[r][c] + dt * f0);
      sm.X[swz(r, c + 1)] = f2bf(sm.Y[r][c + 1] + dt * f1);
      sm.X[swz(r, c + 2)] = f2bf(sm.Y[r][c + 2] + dt * f2);
      sm.X[swz(r, c + 3)] = f2bf(sm.Y[r][c + 3] + dt * f3);
    }
    __syncthreads();

    // ---- stage 2
    PH(exB, 1);
    ++nb;
    arrive();
    waitc(nb);
    // consume1: Heun update; stage X for next step; commit dx
    {
      int r = tid >> 5, c = (tid & 31) << 2;
      const float* src = exB + (size_t)(gb + r) * HH + c;
      float f0 = aload(src), f1 = aload(src + 1), f2 = aload(src + 2), f3 = aload(src + 3);
      float y0n = sm.Y[r][c] + hdt * (sm.K1[r][c] + f0);
      float y1n = sm.Y[r][c + 1] + hdt * (sm.K1[r][c + 1] + f1);
      float y2n = sm.Y[r][c + 2] + hdt * (sm.K1[r][c + 2] + f2);
      float y3n = sm.Y[r][c + 3] + hdt * (sm.K1[r][c + 3] + f3);
      sm.Y[r][c] = y0n; sm.Y[r][c + 1] = y1n; sm.Y[r][c + 2] = y2n; sm.Y[r][c + 3] = y3n;
      sm.X[swz(r, c)] = f2bf(y0n);
      sm.X[swz(r, c + 1)] = f2bf(y1n);
      sm.X[swz(r, c + 2)] = f2bf(y2n);
      sm.X[swz(r, c + 3)] = f2bf(y3n);
      int which = tid >> 8, rr = (tid >> 4) & 15, d = tid & 15;
      sm.dx[which][rr][d] = pc2 + 2.0f * ptau * pc1 + 3.0f * ptau * ptau * pc0;
    }
    __syncthreads();
  }

  // ---- classifier + softmax (slice 0 only)
  if (s16 == 0) {
    if (tid < G * NLBL) {
      int r = tid / NLBL, c = tid % NLBL;
      float s = bl2[c];
      const float* wr = Wl2 + (size_t)c * HH;
#pragma unroll 4
      for (int h = 0; h < HH; ++h) s += sm.Y[r][h] * wr[h];
      sm.logits[tid] = s;
    }
    __syncthreads();
    if (tid < G) {
      float mx = -1e30f;
#pragma unroll
      for (int c = 0; c < NLBL; ++c) mx = fmaxf(mx, sm.logits[tid * NLBL + c]);
      float e[NLBL], sum = 0.f;
#pragma unroll
      for (int c = 0; c < NLBL; ++c) { e[c] = expf(sm.logits[tid * NLBL + c] - mx); sum += e[c]; }
      float inv = 1.0f / sum;
#pragma unroll
      for (int c = 0; c < NLBL; ++c) out[(size_t)(gb + tid) * NLBL + c] = e[c] * inv;
    }
  }
}

extern "C" void kernel_launch(void* const* d_in, const int* in_sizes, int n_in,
                              void* d_out, int out_size, void* d_ws, size_t ws_size,
                              hipStream_t stream) {
  (void)in_sizes; (void)n_in; (void)out_size; (void)ws_size;
  const float* ts = (const float*)d_in[0];
  const float* coeffs = (const float*)d_in[1];
  const float* x0 = (const float*)d_in[2];
  const float* W1 = (const float*)d_in[3];
  const float* b1 = (const float*)d_in[4];
  const float* W2 = (const float*)d_in[5];
  const float* b2 = (const float*)d_in[6];
  const float* W3 = (const float*)d_in[7];
  const float* b3 = (const float*)d_in[8];
  const float* Wl1 = (const float*)d_in[9];
  const float* bl1 = (const float*)d_in[10];
  const float* Wl2 = (const float*)d_in[11];
  const float* bl2 = (const float*)d_in[12];

  char* ws = (char*)d_ws;
  // [0,512K): q8 fp8 W3 (dead after prologue) ALIASED with exA [0,256K) + exB [256K,512K)
  uint2* q8 = (uint2*)ws;
  float* exA = (float*)ws;
  float* exB = (float*)(ws + 262144);
  float* w3s = (float*)(ws + 524288);                  // 8KB row scales
  unsigned int* flags = (unsigned int*)(ws + 532480);  // 36KB: 256 padded flags + init ctr

  static_assert(sizeof(SM) <= 160 * 1024, "LDS overflow");
  hipFuncSetAttribute(reinterpret_cast<const void*>(cde_main),
                      hipFuncAttributeMaxDynamicSharedMemorySize, (int)sizeof(SM));

  hipMemsetAsync(flags, 0, 36864, stream);
  prep_scale<<<512, 256, 0, stream>>>(W3, w3s);
  prep_pack<<<256, 256, 0, stream>>>(W3, w3s, q8);

  float* outp = (float*)d_out;
  void* args[] = {&ts, &coeffs, &x0, &b1, &b2, &b3, &Wl1, &bl1, &Wl2, &bl2,
                  &W1, &W2, &q8, &w3s, &exA, &exB, &flags, &outp};
  hipLaunchCooperativeKernel(reinterpret_cast<const void*>(cde_main), dim3(NWG), dim3(NTHR),
                             args, (unsigned int)sizeof(SM), stream);
}

// Round 13
// 3314.944 us; speedup vs baseline: 1.2200x; 1.2200x over previous
//
#include <hip/hip_runtime.h>

#define BB 512
#define LL 2000
#define DD 16
#define HH 128
#define WD 256
#define NLBL 10
#define NSTEPS 500
#define G 16
#define NSL 8             // h-slices per batch-group
#define NGRP (BB / G)     // 32 groups
#define NWG (NGRP * NSL)  // 256 workgroups (1 per CU)
#define NTHR 512
#define X8S 35            // X8w row stride in u64 (bank-conflict fix)

typedef __bf16 bf16x8 __attribute__((ext_vector_type(8)));
typedef float f32x4 __attribute__((ext_vector_type(4)));

__device__ __forceinline__ float aload(const float* p) {
  return __hip_atomic_load(p, __ATOMIC_RELAXED, __HIP_MEMORY_SCOPE_AGENT);
}
__device__ __forceinline__ void astore(float* p, float v) {
  __hip_atomic_store(p, v, __ATOMIC_RELAXED, __HIP_MEMORY_SCOPE_AGENT);
}
__device__ __forceinline__ unsigned int aloadu(const unsigned int* p) {
  return __hip_atomic_load(p, __ATOMIC_RELAXED, __HIP_MEMORY_SCOPE_AGENT);
}

__device__ __forceinline__ unsigned short f2bf(float f) {
  unsigned int u = __float_as_uint(f);
  u += 0x7FFFu + ((u >> 16) & 1u);
  return (unsigned short)(u >> 16);
}
__device__ __forceinline__ unsigned int pk2bf(float a, float b) {
  return (unsigned int)f2bf(a) | ((unsigned int)f2bf(b) << 16);
}

// XOR-swizzled element offset into a [rows][256] bf16 LDS tile (16B chunks)
__device__ __forceinline__ int swz(int r, int c) {
  return r * WD + ((((c >> 3) ^ (r & 7)) << 3) | (c & 7));
}

__device__ __forceinline__ bf16x8 ldfrag(const unsigned short* buf, int row, int chunk) {
  return *reinterpret_cast<const bf16x8*>(buf + row * WD + ((chunk ^ (row & 7)) << 3));
}

// OCP e4m3fn encode, RNE (prep only)
__device__ unsigned char enc_e4m3(float x) {
  float ax = fabsf(x);
  unsigned char sg = (unsigned char)((__float_as_uint(x) >> 24) & 0x80u);
  if (ax > 448.f) ax = 448.f;
  if (ax < 0.001953125f) {
    int m = (int)rintf(ax * 512.f);
    return sg | (unsigned char)m;
  }
  unsigned int u = __float_as_uint(ax);
  unsigned int r = u + 0x7FFFFu + ((u >> 20) & 1u);
  r &= 0xFFF00000u;
  int e = (int)(r >> 23) - 127;
  if (e < -6) {
    int m = (int)rintf(ax * 512.f);
    if (m >= 8) return sg | 0x08;
    return sg | (unsigned char)m;
  }
  if (e > 8) return sg | 0x7E;
  unsigned int m = (r >> 20) & 7u;
  return sg | (unsigned char)(((e + 7) << 3) | m);
}

// pack 4 f32 -> 4 fp8 e4m3 bytes in one uint
__device__ __forceinline__ unsigned int pk4_fp8(float a, float b, float c, float d) {
#if __has_builtin(__builtin_amdgcn_cvt_pk_fp8_f32)
  int w0 = __builtin_amdgcn_cvt_pk_fp8_f32(a, b, 0, false);
  w0 = __builtin_amdgcn_cvt_pk_fp8_f32(c, d, w0, true);
  return (unsigned int)w0;
#else
  return (unsigned int)enc_e4m3(a) | ((unsigned int)enc_e4m3(b) << 8) |
         ((unsigned int)enc_e4m3(c) << 16) | ((unsigned int)enc_e4m3(d) << 24);
#endif
}

struct __align__(16) SM {
  uint2 q8l[16 * 512];                 // 64KB: slice W3 fp8, frag-major (16 h-tiles)
  float Y[G][HH];                      // 8K
  float K1[G][HH];                     // 8K (full, from exchange)
  unsigned short X[G * WD];            // 8K swizzled bf16 activations
  unsigned short Hb[G * WD];           // 8K swizzled bf16 H1
  unsigned long long X8w[G * X8S];     // H2 fp8 packed, 280B/row (bank fix)
  float dx[2][G][DD];                  // [stage][row][d]
  float b1[WD], b2[WD];
  float2 sb3[256];                     // {w3 row scale, b3} for owned slice
  float tsl[LL];
  float tau_tab[2 * NSTEPS];
  unsigned short idx_tab[2 * NSTEPS];
  float logits[G * NLBL];
};

// per-row absmax -> scale = max/240
__global__ void prep_scale(const float* __restrict__ W3, float* __restrict__ w3s) {
  int row = blockIdx.x * 4 + (threadIdx.x >> 6);
  int lane = threadIdx.x & 63;
  const float* wr = W3 + (size_t)row * WD;
  float m = 0.f;
#pragma unroll
  for (int i = 0; i < 4; ++i) m = fmaxf(m, fabsf(wr[lane + 64 * i]));
#pragma unroll
  for (int off = 32; off >= 1; off >>= 1) m = fmaxf(m, __shfl_xor(m, off));
  if (lane == 0) w3s[row] = fmaxf(m, 1e-30f) * (1.0f / 240.0f);
}

// pack W3 into frag-major fp8: uint2 index o = nt*512 + s*64 + lane
// holds bytes k = s*32 + (lane>>4)*8 + j of W3 row nt*16 + (lane&15)
__global__ void prep_pack(const float* __restrict__ W3, const float* __restrict__ w3s,
                          uint2* __restrict__ q8) {
  int o = blockIdx.x * blockDim.x + threadIdx.x;  // 65536
  int lane = o & 63, s = (o >> 6) & 7, nt = o >> 9;
  int row = nt * 16 + (lane & 15);
  int k0 = s * 32 + ((lane >> 4) << 3);
  float inv = 1.0f / w3s[row];
  const float* src = W3 + (size_t)row * WD + k0;
  unsigned int lo = 0, hi = 0;
#pragma unroll
  for (int j = 0; j < 4; ++j) lo |= (unsigned int)enc_e4m3(src[j] * inv) << (8 * j);
#pragma unroll
  for (int j = 0; j < 4; ++j) hi |= (unsigned int)enc_e4m3(src[4 + j] * inv) << (8 * j);
  q8[o] = make_uint2(lo, hi);
}

__global__ __launch_bounds__(NTHR, 2) void cde_main(
    const float* __restrict__ ts, const float* __restrict__ coeffs,
    const float* __restrict__ x0,
    const float* __restrict__ b1g, const float* __restrict__ b2g, const float* __restrict__ b3g,
    const float* __restrict__ Wl1, const float* __restrict__ bl1,
    const float* __restrict__ Wl2, const float* __restrict__ bl2,
    const float* __restrict__ W1, const float* __restrict__ W2,
    const uint2* __restrict__ q8g, const float* __restrict__ w3s,
    float* __restrict__ exA, float* __restrict__ exB,
    unsigned int* __restrict__ flags,
    float* __restrict__ out) {
  extern __shared__ char smraw[];
  SM& sm = *reinterpret_cast<SM*>(smraw);
  const int tid = threadIdx.x;
  const int bid = blockIdx.x;
  const int g = bid & 31, s16 = bid >> 5;  // group's 8 slices share bid%8 -> same XCD
  const int gb = g * G;
  const int w = tid >> 6, lane = tid & 63;
  const int row16 = lane & 15, kg = lane >> 4;

  const float ts0 = ts[0];
  const float dt = (ts[LL - 1] - ts0) / (float)NSTEPS;
  const float hdt = 0.5f * dt;

  // ---- prologue: LDS fills
  for (int i = tid; i < LL; i += NTHR) sm.tsl[i] = ts[i];
  for (int i = tid; i < WD; i += NTHR) { sm.b1[i] = b1g[i]; sm.b2[i] = b2g[i]; }
  for (int i = tid; i < 256; i += NTHR) {
    int rg = s16 * 256 + i;
    sm.sb3[i] = make_float2(w3s[rg], b3g[rg]);
  }
  for (int i = tid; i < 16 * 512; i += NTHR) sm.q8l[i] = q8g[s16 * 8192 + i];

  // y0 = x0 @ Wl1^T + bl1; stage X for k=0 stage-1
  for (int i = tid; i < G * HH; i += NTHR) {
    int r = i >> 7, h = i & (HH - 1);
    float s = bl1[h];
    const float* xr = x0 + (size_t)(gb + r) * DD;
    const float* wr = Wl1 + (size_t)h * DD;
#pragma unroll
    for (int d = 0; d < DD; ++d) s += xr[d] * wr[d];
    sm.Y[r][h] = s;
    sm.X[swz(r, h)] = f2bf(s);
  }

  // persistent W1/W2 fragments (lane&15 = weight-row index; used as A-operand)
  bf16x8 w1f[2][4], w2f[2][8];
#pragma unroll
  for (int tt = 0; tt < 2; ++tt) {
    int n = (w + tt * 8) * 16 + row16;
#pragma unroll
    for (int s = 0; s < 4; ++s) {
      bf16x8 v;
#pragma unroll
      for (int e = 0; e < 8; ++e)
        v[e] = __builtin_bit_cast(__bf16, f2bf(W1[(size_t)n * HH + (s * 4 + kg) * 8 + e]));
      w1f[tt][s] = v;
    }
#pragma unroll
    for (int s = 0; s < 8; ++s) {
      bf16x8 v;
#pragma unroll
      for (int e = 0; e < 8; ++e)
        v[e] = __builtin_bit_cast(__bf16, f2bf(W2[(size_t)n * WD + (s * 4 + kg) * 8 + e]));
      w2f[tt][s] = v;
    }
  }
  __syncthreads();

  // idx/tau tables (bit-faithful to reference arithmetic)
  for (int e = tid; e < 2 * NSTEPS; e += NTHR) {
    int kk = e >> 1;
    float t = ts0 + (float)kk * dt;
    if (e & 1) t = t + dt;
    int lo = 0, hi = LL;
    while (lo < hi) { int m = (lo + hi) >> 1; if (sm.tsl[m] <= t) lo = m + 1; else hi = m; }
    int idx = lo - 1;
    if (idx < 0) idx = 0;
    if (idx > LL - 2) idx = LL - 2;
    sm.idx_tab[e] = (unsigned short)idx;
    sm.tau_tab[e] = t - sm.tsl[idx];
  }
  __syncthreads();

  // dx for step 0 (both stages)
  {
    int which = tid >> 8, rr = (tid >> 4) & 15, d = tid & 15;
    int idx = sm.idx_tab[which];
    float tau = sm.tau_tab[which];
    const float* cb = coeffs + ((size_t)(gb + rr) * 4 * (LL - 1) + idx) * DD + d;
    float c0 = cb[0];
    float c1 = cb[(size_t)(LL - 1) * DD];
    float c2 = cb[(size_t)2 * (LL - 1) * DD];
    sm.dx[which][rr][d] = c2 + 2.0f * tau * c1 + 3.0f * tau * tau * c0;
  }

  // ---- global init barrier (one-time): done reading q8g (ex* alias it)
  {
    unsigned int* ic = &flags[1024];
    __syncthreads();
    if (tid == 0) {
      atomicAdd(ic, 1u);
      while (aloadu(ic) < NWG) __builtin_amdgcn_s_sleep(1);
    }
    __syncthreads();
  }

  float pc0 = 0.f, pc1 = 0.f, pc2 = 0.f, ptau = 0.f;  // next-step coeff prefetch
  unsigned int nb = 0;
  unsigned int* gctr = &flags[g * 32];  // 128B-padded per-group counter

  // ---- one vf eval: B,C,D on staged X; K-slice -> exDst
  auto PH = [&](float* exDst, int stage) {
    // phase B (swapped): H1 = relu(X @ W1^T + b1); lane -> 4 consecutive h1, 1 batch
    {
      bf16x8 a[4];
#pragma unroll
      for (int s = 0; s < 4; ++s) a[s] = ldfrag(sm.X, row16, s * 4 + kg);
#pragma unroll
      for (int tt = 0; tt < 2; ++tt) {
        const int T = w + tt * 8;
        f32x4 acc = {0.f, 0.f, 0.f, 0.f};
#pragma unroll
        for (int s = 0; s < 4; ++s)
          acc = __builtin_amdgcn_mfma_f32_16x16x32_bf16(w1f[tt][s], a[s], acc, 0, 0, 0);
        const int h1b = T * 16 + kg * 4;
        const float4 b14 = *reinterpret_cast<const float4*>(&sm.b1[h1b]);
        float o0 = fmaxf(acc[0] + b14.x, 0.f);
        float o1 = fmaxf(acc[1] + b14.y, 0.f);
        float o2 = fmaxf(acc[2] + b14.z, 0.f);
        float o3 = fmaxf(acc[3] + b14.w, 0.f);
        // store 4 bf16 (elems h1b..h1b+3 of row row16) at swizzled chunk
        int cp = ((2 * T + (kg >> 1)) ^ (row16 & 7));
        uint2* dst = reinterpret_cast<uint2*>(sm.Hb + row16 * WD + cp * 8 + (kg & 1) * 4);
        *dst = make_uint2(pk2bf(o0, o1), pk2bf(o2, o3));
      }
    }
    __syncthreads();

    // phase C (swapped): H2 = relu(H1 @ W2^T + b2), packed fp8 -> X8w
    {
      bf16x8 hb[8];
#pragma unroll
      for (int s = 0; s < 8; ++s) hb[s] = ldfrag(sm.Hb, row16, s * 4 + kg);
      unsigned int* x8u = reinterpret_cast<unsigned int*>(sm.X8w);
#pragma unroll
      for (int tt = 0; tt < 2; ++tt) {
        const int T = w + tt * 8;
        f32x4 acc = {0.f, 0.f, 0.f, 0.f};
#pragma unroll
        for (int s = 0; s < 8; ++s)
          acc = __builtin_amdgcn_mfma_f32_16x16x32_bf16(w2f[tt][s], hb[s], acc, 0, 0, 0);
        const int nbi = T * 16 + kg * 4;
        const float4 b24 = *reinterpret_cast<const float4*>(&sm.b2[nbi]);
        float o0 = fmaxf(acc[0] + b24.x, 0.f);
        float o1 = fmaxf(acc[1] + b24.y, 0.f);
        float o2 = fmaxf(acc[2] + b24.z, 0.f);
        float o3 = fmaxf(acc[3] + b24.w, 0.f);
        x8u[row16 * (2 * X8S) + T * 4 + kg] = pk4_fp8(o0, o1, o2, o3);
      }
    }
    __syncthreads();

    // phase D: O = tanh(H2 @ W3^T + b3); K_slice = sum_d O*dX
    {
      long b8[8];
#pragma unroll
      for (int s = 0; s < 8; ++s)
        b8[s] = __builtin_bit_cast(long, sm.X8w[row16 * X8S + s * 4 + kg]);
      const float4 dx4 = *reinterpret_cast<const float4*>(&sm.dx[stage][row16][kg * 4]);
#pragma unroll
      for (int j = 0; j < 2; ++j) {
        const int ntl = w + j * 8;  // local h (0..15)
        const uint2* wp = sm.q8l + ntl * 512 + lane;
        f32x4 acc = {0.f, 0.f, 0.f, 0.f};
#pragma unroll
        for (int s = 0; s < 8; ++s)
          acc = __builtin_amdgcn_mfma_f32_16x16x32_fp8_fp8(
              __builtin_bit_cast(long, wp[s * 64]), b8[s], acc, 0, 0, 0);
        const float4* sb4 = reinterpret_cast<const float4*>(&sm.sb3[ntl * 16 + kg * 4]);
        float4 sba = sb4[0], sbb = sb4[1];
        float psum = 0.f;
        {
          float o = acc[0] * sba.x + sba.y;
          float e2 = __expf(2.0f * o);
          psum += (1.0f - 2.0f / (e2 + 1.0f)) * dx4.x;
          o = acc[1] * sba.z + sba.w;
          e2 = __expf(2.0f * o);
          psum += (1.0f - 2.0f / (e2 + 1.0f)) * dx4.y;
          o = acc[2] * sbb.x + sbb.y;
          e2 = __expf(2.0f * o);
          psum += (1.0f - 2.0f / (e2 + 1.0f)) * dx4.z;
          o = acc[3] * sbb.z + sbb.w;
          e2 = __expf(2.0f * o);
          psum += (1.0f - 2.0f / (e2 + 1.0f)) * dx4.w;
        }
        psum += __shfl_xor(psum, 16);
        psum += __shfl_xor(psum, 32);
        if (kg == 0) astore(exDst + (size_t)(gb + row16) * HH + (s16 * 16 + ntl), psum);
      }
    }
  };

  // arrive: syncthreads drains exchange stores; one RMW to the hot counter line
  auto arrive = [&]() {
    __syncthreads();
    if (tid == 0) atomicAdd(gctr, 1u);
  };
  auto waitc = [&](unsigned int tgt) {
    if (tid == 0)
      while (aloadu(gctr) < tgt) __builtin_amdgcn_s_sleep(1);
    __syncthreads();
  };

  for (int k = 0; k < NSTEPS; ++k) {
    // ---- stage 1 (X staged by prologue / previous consume1)
    {
      int which = tid >> 8, rr = (tid >> 4) & 15, d = tid & 15;
      int e = 2 * (k + 1) + which;
      if (e > 2 * NSTEPS - 1) e = 2 * NSTEPS - 1;
      int idx = sm.idx_tab[e];
      ptau = sm.tau_tab[e];
      const float* cb = coeffs + ((size_t)(gb + rr) * 4 * (LL - 1) + idx) * DD + d;
      pc0 = cb[0];
      pc1 = cb[(size_t)(LL - 1) * DD];
      pc2 = cb[(size_t)2 * (LL - 1) * DD];
    }
    PH(exA, 0);
    arrive();
    waitc(++nb * NSL);
    // consume0: K1 <- exA; stage X = f2bf(Y + dt*K1)
    {
      int r = tid >> 5, c = (tid & 31) << 2;
      const float* src = exA + (size_t)(gb + r) * HH + c;
      float f0 = aload(src), f1 = aload(src + 1), f2 = aload(src + 2), f3 = aload(src + 3);
      sm.K1[r][c] = f0; sm.K1[r][c + 1] = f1; sm.K1[r][c + 2] = f2; sm.K1[r][c + 3] = f3;
      sm.X[swz(r, c)] = f2bf(sm.Y[r][c] + dt * f0);
      sm.X[swz(r, c + 1)] = f2bf(sm.Y[r][c + 1] + dt * f1);
      sm.X[swz(r, c + 2)] = f2bf(sm.Y[r][c + 2] + dt * f2);
      sm.X[swz(r, c + 3)] = f2bf(sm.Y[r][c + 3] + dt * f3);
    }
    __syncthreads();

    // ---- stage 2
    PH(exB, 1);
    arrive();
    waitc(++nb * NSL);
    // consume1: Heun update; stage X for next step; commit dx
    {
      int r = tid >> 5, c = (tid & 31) << 2;
      const float* src = exB + (size_t)(gb + r) * HH + c;
      float f0 = aload(src), f1 = aload(src + 1), f2 = aload(src + 2), f3 = aload(src + 3);
      float y0n = sm.Y[r][c] + hdt * (sm.K1[r][c] + f0);
      float y1n = sm.Y[r][c + 1] + hdt * (sm.K1[r][c + 1] + f1);
      float y2n = sm.Y[r][c + 2] + hdt * (sm.K1[r][c + 2] + f2);
      float y3n = sm.Y[r][c + 3] + hdt * (sm.K1[r][c + 3] + f3);
      sm.Y[r][c] = y0n; sm.Y[r][c + 1] = y1n; sm.Y[r][c + 2] = y2n; sm.Y[r][c + 3] = y3n;
      sm.X[swz(r, c)] = f2bf(y0n);
      sm.X[swz(r, c + 1)] = f2bf(y1n);
      sm.X[swz(r, c + 2)] = f2bf(y2n);
      sm.X[swz(r, c + 3)] = f2bf(y3n);
      int which = tid >> 8, rr = (tid >> 4) & 15, d = tid & 15;
      sm.dx[which][rr][d] = pc2 + 2.0f * ptau * pc1 + 3.0f * ptau * ptau * pc0;
    }
    __syncthreads();
  }

  // ---- classifier + softmax (slice 0 only)
  if (s16 == 0) {
    if (tid < G * NLBL) {
      int r = tid / NLBL, c = tid % NLBL;
      float s = bl2[c];
      const float* wr = Wl2 + (size_t)c * HH;
#pragma unroll 4
      for (int h = 0; h < HH; ++h) s += sm.Y[r][h] * wr[h];
      sm.logits[tid] = s;
    }
    __syncthreads();
    if (tid < G) {
      float mx = -1e30f;
#pragma unroll
      for (int c = 0; c < NLBL; ++c) mx = fmaxf(mx, sm.logits[tid * NLBL + c]);
      float e[NLBL], sum = 0.f;
#pragma unroll
      for (int c = 0; c < NLBL; ++c) { e[c] = expf(sm.logits[tid * NLBL + c] - mx); sum += e[c]; }
      float inv = 1.0f / sum;
#pragma unroll
      for (int c = 0; c < NLBL; ++c) out[(size_t)(gb + tid) * NLBL + c] = e[c] * inv;
    }
  }
}

extern "C" void kernel_launch(void* const* d_in, const int* in_sizes, int n_in,
                              void* d_out, int out_size, void* d_ws, size_t ws_size,
                              hipStream_t stream) {
  (void)in_sizes; (void)n_in; (void)out_size; (void)ws_size;
  const float* ts = (const float*)d_in[0];
  const float* coeffs = (const float*)d_in[1];
  const float* x0 = (const float*)d_in[2];
  const float* W1 = (const float*)d_in[3];
  const float* b1 = (const float*)d_in[4];
  const float* W2 = (const float*)d_in[5];
  const float* b2 = (const float*)d_in[6];
  const float* W3 = (const float*)d_in[7];
  const float* b3 = (const float*)d_in[8];
  const float* Wl1 = (const float*)d_in[9];
  const float* bl1 = (const float*)d_in[10];
  const float* Wl2 = (const float*)d_in[11];
  const float* bl2 = (const float*)d_in[12];

  char* ws = (char*)d_ws;
  // [0,512K): q8 fp8 W3 (dead after prologue) ALIASED with exA [0,256K) + exB [256K,512K)
  uint2* q8 = (uint2*)ws;
  float* exA = (float*)ws;
  float* exB = (float*)(ws + 262144);
  float* w3s = (float*)(ws + 524288);                  // 8KB row scales
  unsigned int* flags = (unsigned int*)(ws + 532480);  // 8KB padded counters

  static_assert(sizeof(SM) <= 160 * 1024, "LDS overflow");
  hipFuncSetAttribute(reinterpret_cast<const void*>(cde_main),
                      hipFuncAttributeMaxDynamicSharedMemorySize, (int)sizeof(SM));

  hipMemsetAsync(flags, 0, 8192, stream);
  prep_scale<<<512, 256, 0, stream>>>(W3, w3s);
  prep_pack<<<256, 256, 0, stream>>>(W3, w3s, q8);

  float* outp = (float*)d_out;
  void* args[] = {&ts, &coeffs, &x0, &b1, &b2, &b3, &Wl1, &bl1, &Wl2, &bl2,
                  &W1, &W2, &q8, &w3s, &exA, &exB, &flags, &outp};
  hipLaunchCooperativeKernel(reinterpret_cast<const void*>(cde_main), dim3(NWG), dim3(NTHR),
                             args, (unsigned int)sizeof(SM), stream);
}

// Round 14
// 3189.035 us; speedup vs baseline: 1.2681x; 1.0395x over previous
//
#include <hip/hip_runtime.h>

#define BB 512
#define LL 2000
#define DD 16
#define HH 128
#define WD 256
#define NLBL 10
#define NSTEPS 500
#define G 16
#define NSL 8             // h-slices per batch-group
#define NGRP (BB / G)     // 32 groups
#define NWG (NGRP * NSL)  // 256 workgroups (1 per CU)
#define NTHR 512
#define X8S 35            // X8w row stride in u64

typedef __bf16 bf16x8 __attribute__((ext_vector_type(8)));
typedef float f32x4 __attribute__((ext_vector_type(4)));

__device__ __forceinline__ float aload(const float* p) {
  return __hip_atomic_load(p, __ATOMIC_RELAXED, __HIP_MEMORY_SCOPE_AGENT);
}
__device__ __forceinline__ void astore(float* p, float v) {
  __hip_atomic_store(p, v, __ATOMIC_RELAXED, __HIP_MEMORY_SCOPE_AGENT);
}
__device__ __forceinline__ unsigned int aloadu(const unsigned int* p) {
  return __hip_atomic_load(p, __ATOMIC_RELAXED, __HIP_MEMORY_SCOPE_AGENT);
}

__device__ __forceinline__ unsigned short f2bf(float f) {
  unsigned int u = __float_as_uint(f);
  u += 0x7FFFu + ((u >> 16) & 1u);
  return (unsigned short)(u >> 16);
}
__device__ __forceinline__ unsigned int pk2bf(float a, float b) {
  return (unsigned int)f2bf(a) | ((unsigned int)f2bf(b) << 16);
}

// XOR-swizzled element offset into a [rows][256] bf16 LDS tile (16B chunks)
__device__ __forceinline__ int swz(int r, int c) {
  return r * WD + ((((c >> 3) ^ (r & 7)) << 3) | (c & 7));
}

__device__ __forceinline__ bf16x8 ldfrag(const unsigned short* buf, int row, int chunk) {
  return *reinterpret_cast<const bf16x8*>(buf + row * WD + ((chunk ^ (row & 7)) << 3));
}

// OCP e4m3fn encode, RNE (prep only)
__device__ unsigned char enc_e4m3(float x) {
  float ax = fabsf(x);
  unsigned char sg = (unsigned char)((__float_as_uint(x) >> 24) & 0x80u);
  if (ax > 448.f) ax = 448.f;
  if (ax < 0.001953125f) {
    int m = (int)rintf(ax * 512.f);
    return sg | (unsigned char)m;
  }
  unsigned int u = __float_as_uint(ax);
  unsigned int r = u + 0x7FFFFu + ((u >> 20) & 1u);
  r &= 0xFFF00000u;
  int e = (int)(r >> 23) - 127;
  if (e < -6) {
    int m = (int)rintf(ax * 512.f);
    if (m >= 8) return sg | 0x08;
    return sg | (unsigned char)m;
  }
  if (e > 8) return sg | 0x7E;
  unsigned int m = (r >> 20) & 7u;
  return sg | (unsigned char)(((e + 7) << 3) | m);
}

// pack 4 f32 -> 4 fp8 e4m3 bytes in one uint
__device__ __forceinline__ unsigned int pk4_fp8(float a, float b, float c, float d) {
#if __has_builtin(__builtin_amdgcn_cvt_pk_fp8_f32)
  int w0 = __builtin_amdgcn_cvt_pk_fp8_f32(a, b, 0, false);
  w0 = __builtin_amdgcn_cvt_pk_fp8_f32(c, d, w0, true);
  return (unsigned int)w0;
#else
  return (unsigned int)enc_e4m3(a) | ((unsigned int)enc_e4m3(b) << 8) |
         ((unsigned int)enc_e4m3(c) << 16) | ((unsigned int)enc_e4m3(d) << 24);
#endif
}

struct __align__(16) SM {
  uint2 q8l[16 * 512];                 // 64KB: slice W3 fp8, frag-major (16 h-tiles)
  float Y[G][HH];                      // 8K
  float K1[G][HH];                     // 8K (full, from exchange)
  unsigned short X[G * WD];            // 8K swizzled bf16 activations
  unsigned short Hb[G * WD];           // 8K swizzled bf16 H1
  unsigned long long X8w[G * X8S];     // H2 fp8 packed
  float dx[2][G][DD];                  // [stage][row][d]
  float b1[WD], b2[WD];
  float2 sb3[256];                     // {w3 row scale, b3} for owned slice
  float tsl[LL];
  float tau_tab[2 * NSTEPS];
  unsigned short idx_tab[2 * NSTEPS];
  float logits[G * NLBL];
};

// per-row absmax -> scale = max/240
__global__ void prep_scale(const float* __restrict__ W3, float* __restrict__ w3s) {
  int row = blockIdx.x * 4 + (threadIdx.x >> 6);
  int lane = threadIdx.x & 63;
  const float* wr = W3 + (size_t)row * WD;
  float m = 0.f;
#pragma unroll
  for (int i = 0; i < 4; ++i) m = fmaxf(m, fabsf(wr[lane + 64 * i]));
#pragma unroll
  for (int off = 32; off >= 1; off >>= 1) m = fmaxf(m, __shfl_xor(m, off));
  if (lane == 0) w3s[row] = fmaxf(m, 1e-30f) * (1.0f / 240.0f);
}

// pack W3 into frag-major fp8: uint2 index o = nt*512 + s*64 + lane
// holds bytes k = s*32 + (lane>>4)*8 + j of W3 row nt*16 + (lane&15)
__global__ void prep_pack(const float* __restrict__ W3, const float* __restrict__ w3s,
                          uint2* __restrict__ q8) {
  int o = blockIdx.x * blockDim.x + threadIdx.x;  // 65536
  int lane = o & 63, s = (o >> 6) & 7, nt = o >> 9;
  int row = nt * 16 + (lane & 15);
  int k0 = s * 32 + ((lane >> 4) << 3);
  float inv = 1.0f / w3s[row];
  const float* src = W3 + (size_t)row * WD + k0;
  unsigned int lo = 0, hi = 0;
#pragma unroll
  for (int j = 0; j < 4; ++j) lo |= (unsigned int)enc_e4m3(src[j] * inv) << (8 * j);
#pragma unroll
  for (int j = 0; j < 4; ++j) hi |= (unsigned int)enc_e4m3(src[4 + j] * inv) << (8 * j);
  q8[o] = make_uint2(lo, hi);
}

__global__ __launch_bounds__(NTHR, 2) void cde_main(
    const float* __restrict__ ts, const float* __restrict__ coeffs,
    const float* __restrict__ x0,
    const float* __restrict__ b1g, const float* __restrict__ b2g, const float* __restrict__ b3g,
    const float* __restrict__ Wl1, const float* __restrict__ bl1,
    const float* __restrict__ Wl2, const float* __restrict__ bl2,
    const float* __restrict__ W1, const float* __restrict__ W2,
    const uint2* __restrict__ q8g, const float* __restrict__ w3s,
    float* __restrict__ exA, float* __restrict__ exB,
    unsigned int* __restrict__ flags,
    float* __restrict__ out) {
  extern __shared__ char smraw[];
  SM& sm = *reinterpret_cast<SM*>(smraw);
  const int tid = threadIdx.x;
  const int bid = blockIdx.x;
  const int g = bid & 31, s16 = bid >> 5;  // group's 8 slices share bid%8 -> same XCD
  const int gb = g * G;
  const int w = tid >> 6, lane = tid & 63;
  const int row16 = lane & 15, kg = lane >> 4;

  const float ts0 = ts[0];
  const float dt = (ts[LL - 1] - ts0) / (float)NSTEPS;
  const float hdt = 0.5f * dt;

  // ---- prologue: LDS fills
  for (int i = tid; i < LL; i += NTHR) sm.tsl[i] = ts[i];
  for (int i = tid; i < WD; i += NTHR) { sm.b1[i] = b1g[i]; sm.b2[i] = b2g[i]; }
  for (int i = tid; i < 256; i += NTHR) {
    int rg = s16 * 256 + i;
    sm.sb3[i] = make_float2(w3s[rg], b3g[rg]);
  }
  for (int i = tid; i < 16 * 512; i += NTHR) sm.q8l[i] = q8g[s16 * 8192 + i];

  // y0 = x0 @ Wl1^T + bl1; stage X for k=0 stage-1
  for (int i = tid; i < G * HH; i += NTHR) {
    int r = i >> 7, h = i & (HH - 1);
    float s = bl1[h];
    const float* xr = x0 + (size_t)(gb + r) * DD;
    const float* wr = Wl1 + (size_t)h * DD;
#pragma unroll
    for (int d = 0; d < DD; ++d) s += xr[d] * wr[d];
    sm.Y[r][h] = s;
    sm.X[swz(r, h)] = f2bf(s);
  }

  // persistent W1/W2 fragments (lane&15 = weight-row index; used as A-operand)
  bf16x8 w1f[2][4], w2f[2][8];
#pragma unroll
  for (int tt = 0; tt < 2; ++tt) {
    int n = (w + tt * 8) * 16 + row16;
#pragma unroll
    for (int s = 0; s < 4; ++s) {
      bf16x8 v;
#pragma unroll
      for (int e = 0; e < 8; ++e)
        v[e] = __builtin_bit_cast(__bf16, f2bf(W1[(size_t)n * HH + (s * 4 + kg) * 8 + e]));
      w1f[tt][s] = v;
    }
#pragma unroll
    for (int s = 0; s < 8; ++s) {
      bf16x8 v;
#pragma unroll
      for (int e = 0; e < 8; ++e)
        v[e] = __builtin_bit_cast(__bf16, f2bf(W2[(size_t)n * WD + (s * 4 + kg) * 8 + e]));
      w2f[tt][s] = v;
    }
  }
  __syncthreads();

  // idx/tau tables (bit-faithful to reference arithmetic)
  for (int e = tid; e < 2 * NSTEPS; e += NTHR) {
    int kk = e >> 1;
    float t = ts0 + (float)kk * dt;
    if (e & 1) t = t + dt;
    int lo = 0, hi = LL;
    while (lo < hi) { int m = (lo + hi) >> 1; if (sm.tsl[m] <= t) lo = m + 1; else hi = m; }
    int idx = lo - 1;
    if (idx < 0) idx = 0;
    if (idx > LL - 2) idx = LL - 2;
    sm.idx_tab[e] = (unsigned short)idx;
    sm.tau_tab[e] = t - sm.tsl[idx];
  }
  __syncthreads();

  // dx for step 0 (both stages)
  {
    int which = tid >> 8, rr = (tid >> 4) & 15, d = tid & 15;
    int idx = sm.idx_tab[which];
    float tau = sm.tau_tab[which];
    const float* cb = coeffs + ((size_t)(gb + rr) * 4 * (LL - 1) + idx) * DD + d;
    float c0 = cb[0];
    float c1 = cb[(size_t)(LL - 1) * DD];
    float c2 = cb[(size_t)2 * (LL - 1) * DD];
    sm.dx[which][rr][d] = c2 + 2.0f * tau * c1 + 3.0f * tau * tau * c0;
  }

  // ---- hoist loop-invariant per-thread constants into registers
  float4 b14r[2], b24r[2], sbar[2], sbbr[2];
#pragma unroll
  for (int tt = 0; tt < 2; ++tt) {
    const int T = w + tt * 8;
    b14r[tt] = *reinterpret_cast<const float4*>(&sm.b1[T * 16 + kg * 4]);
    b24r[tt] = *reinterpret_cast<const float4*>(&sm.b2[T * 16 + kg * 4]);
    const float4* sb4 = reinterpret_cast<const float4*>(&sm.sb3[T * 16 + kg * 4]);
    sbar[tt] = sb4[0];
    sbbr[tt] = sb4[1];
  }

  // ---- global init barrier (one-time): done reading q8g (ex* alias it)
  {
    unsigned int* ic = &flags[1024];
    __syncthreads();
    if (tid == 0) {
      atomicAdd(ic, 1u);
      while (aloadu(ic) < NWG) __builtin_amdgcn_s_sleep(1);
    }
    __syncthreads();
  }

  float pc0 = 0.f, pc1 = 0.f, pc2 = 0.f, ptau = 0.f;  // next-step coeff prefetch
  unsigned int nb = 0;
  unsigned int* gctr = &flags[g * 32];  // 128B-padded per-group counter

  // ---- one vf eval: B,C,D on staged X; K-slice -> exDst
  auto PH = [&](float* exDst, int stage) {
    // phase B (swapped): H1 = relu(X @ W1^T + b1); lane -> 4 consecutive h1, 1 batch
    {
      bf16x8 a[4];
#pragma unroll
      for (int s = 0; s < 4; ++s) a[s] = ldfrag(sm.X, row16, s * 4 + kg);
#pragma unroll
      for (int tt = 0; tt < 2; ++tt) {
        const int T = w + tt * 8;
        f32x4 acc = {0.f, 0.f, 0.f, 0.f};
#pragma unroll
        for (int s = 0; s < 4; ++s)
          acc = __builtin_amdgcn_mfma_f32_16x16x32_bf16(w1f[tt][s], a[s], acc, 0, 0, 0);
        float o0 = fmaxf(acc[0] + b14r[tt].x, 0.f);
        float o1 = fmaxf(acc[1] + b14r[tt].y, 0.f);
        float o2 = fmaxf(acc[2] + b14r[tt].z, 0.f);
        float o3 = fmaxf(acc[3] + b14r[tt].w, 0.f);
        int cp = ((2 * T + (kg >> 1)) ^ (row16 & 7));
        uint2* dst = reinterpret_cast<uint2*>(sm.Hb + row16 * WD + cp * 8 + (kg & 1) * 4);
        *dst = make_uint2(pk2bf(o0, o1), pk2bf(o2, o3));
      }
    }
    __syncthreads();

    // phase C (swapped): H2 = relu(H1 @ W2^T + b2), packed fp8 -> X8w
    {
      bf16x8 hb[8];
#pragma unroll
      for (int s = 0; s < 8; ++s) hb[s] = ldfrag(sm.Hb, row16, s * 4 + kg);
      unsigned int* x8u = reinterpret_cast<unsigned int*>(sm.X8w);
#pragma unroll
      for (int tt = 0; tt < 2; ++tt) {
        const int T = w + tt * 8;
        f32x4 acc = {0.f, 0.f, 0.f, 0.f};
#pragma unroll
        for (int s = 0; s < 8; ++s)
          acc = __builtin_amdgcn_mfma_f32_16x16x32_bf16(w2f[tt][s], hb[s], acc, 0, 0, 0);
        float o0 = fmaxf(acc[0] + b24r[tt].x, 0.f);
        float o1 = fmaxf(acc[1] + b24r[tt].y, 0.f);
        float o2 = fmaxf(acc[2] + b24r[tt].z, 0.f);
        float o3 = fmaxf(acc[3] + b24r[tt].w, 0.f);
        x8u[row16 * (2 * X8S) + T * 4 + kg] = pk4_fp8(o0, o1, o2, o3);
      }
    }
    __syncthreads();

    // phase D: O = tanh(H2 @ W3^T + b3); K_slice = sum_d O*dX
    {
      long b8[8];
#pragma unroll
      for (int s = 0; s < 8; ++s)
        b8[s] = __builtin_bit_cast(long, sm.X8w[row16 * X8S + s * 4 + kg]);
      const float4 dx4 = *reinterpret_cast<const float4*>(&sm.dx[stage][row16][kg * 4]);
#pragma unroll
      for (int j = 0; j < 2; ++j) {
        const int ntl = w + j * 8;  // local h (0..15)
        const uint2* wp = sm.q8l + ntl * 512 + lane;
        f32x4 acc = {0.f, 0.f, 0.f, 0.f};
#pragma unroll
        for (int s = 0; s < 8; ++s)
          acc = __builtin_amdgcn_mfma_f32_16x16x32_fp8_fp8(
              __builtin_bit_cast(long, wp[s * 64]), b8[s], acc, 0, 0, 0);
        const float4 sba = sbar[j], sbb = sbbr[j];
        float psum = 0.f;
        {
          float o = acc[0] * sba.x + sba.y;
          float e2 = __expf(2.0f * o);
          psum += (1.0f - 2.0f / (e2 + 1.0f)) * dx4.x;
          o = acc[1] * sba.z + sba.w;
          e2 = __expf(2.0f * o);
          psum += (1.0f - 2.0f / (e2 + 1.0f)) * dx4.y;
          o = acc[2] * sbb.x + sbb.y;
          e2 = __expf(2.0f * o);
          psum += (1.0f - 2.0f / (e2 + 1.0f)) * dx4.z;
          o = acc[3] * sbb.z + sbb.w;
          e2 = __expf(2.0f * o);
          psum += (1.0f - 2.0f / (e2 + 1.0f)) * dx4.w;
        }
        psum += __shfl_xor(psum, 16);
        psum += __shfl_xor(psum, 32);
        if (kg == 0) astore(exDst + (size_t)(gb + row16) * HH + (s16 * 16 + ntl), psum);
      }
    }
  };

  // barrier: drain exchange stores; add with return -> last arriver skips poll
  auto barrier = [&](unsigned int tgt) {
    __syncthreads();
    if (tid == 0) {
      unsigned int old = atomicAdd(gctr, 1u);
      if (old != tgt - 1) {
        int spins = 0;
        while (aloadu(gctr) < tgt) {
          if (++spins > 4) __builtin_amdgcn_s_sleep(1);
        }
      }
    }
    __syncthreads();
  };

  for (int k = 0; k < NSTEPS; ++k) {
    // ---- stage 1 (X staged by prologue / previous consume1)
    {
      int which = tid >> 8, rr = (tid >> 4) & 15, d = tid & 15;
      int e = 2 * (k + 1) + which;
      if (e > 2 * NSTEPS - 1) e = 2 * NSTEPS - 1;
      int idx = sm.idx_tab[e];
      ptau = sm.tau_tab[e];
      const float* cb = coeffs + ((size_t)(gb + rr) * 4 * (LL - 1) + idx) * DD + d;
      pc0 = cb[0];
      pc1 = cb[(size_t)(LL - 1) * DD];
      pc2 = cb[(size_t)2 * (LL - 1) * DD];
    }
    PH(exA, 0);
    barrier(++nb * NSL);
    // consume0: K1 <- exA (float4); stage X = f2bf(Y + dt*K1) (uint2)
    {
      int r = tid >> 5, c = (tid & 31) << 2;
      const float* src = exA + (size_t)(gb + r) * HH + c;
      float f0 = aload(src), f1 = aload(src + 1), f2 = aload(src + 2), f3 = aload(src + 3);
      *reinterpret_cast<float4*>(&sm.K1[r][c]) = make_float4(f0, f1, f2, f3);
      const float4 y4 = *reinterpret_cast<const float4*>(&sm.Y[r][c]);
      uint2* xd = reinterpret_cast<uint2*>(
          sm.X + r * WD + (((c >> 3) ^ (r & 7)) << 3) + (c & 4));
      *xd = make_uint2(pk2bf(y4.x + dt * f0, y4.y + dt * f1),
                       pk2bf(y4.z + dt * f2, y4.w + dt * f3));
    }
    __syncthreads();

    // ---- stage 2
    PH(exB, 1);
    barrier(++nb * NSL);
    // consume1: Heun update (float4); stage X for next step; commit dx
    {
      int r = tid >> 5, c = (tid & 31) << 2;
      const float* src = exB + (size_t)(gb + r) * HH + c;
      float f0 = aload(src), f1 = aload(src + 1), f2 = aload(src + 2), f3 = aload(src + 3);
      const float4 y4 = *reinterpret_cast<const float4*>(&sm.Y[r][c]);
      const float4 k4 = *reinterpret_cast<const float4*>(&sm.K1[r][c]);
      float y0n = y4.x + hdt * (k4.x + f0);
      float y1n = y4.y + hdt * (k4.y + f1);
      float y2n = y4.z + hdt * (k4.z + f2);
      float y3n = y4.w + hdt * (k4.w + f3);
      *reinterpret_cast<float4*>(&sm.Y[r][c]) = make_float4(y0n, y1n, y2n, y3n);
      uint2* xd = reinterpret_cast<uint2*>(
          sm.X + r * WD + (((c >> 3) ^ (r & 7)) << 3) + (c & 4));
      *xd = make_uint2(pk2bf(y0n, y1n), pk2bf(y2n, y3n));
      int which = tid >> 8, rr = (tid >> 4) & 15, d = tid & 15;
      sm.dx[which][rr][d] = pc2 + 2.0f * ptau * pc1 + 3.0f * ptau * ptau * pc0;
    }
    __syncthreads();
  }

  // ---- classifier + softmax (slice 0 only)
  if (s16 == 0) {
    if (tid < G * NLBL) {
      int r = tid / NLBL, c = tid % NLBL;
      float s = bl2[c];
      const float* wr = Wl2 + (size_t)c * HH;
#pragma unroll 4
      for (int h = 0; h < HH; ++h) s += sm.Y[r][h] * wr[h];
      sm.logits[tid] = s;
    }
    __syncthreads();
    if (tid < G) {
      float mx = -1e30f;
#pragma unroll
      for (int c = 0; c < NLBL; ++c) mx = fmaxf(mx, sm.logits[tid * NLBL + c]);
      float e[NLBL], sum = 0.f;
#pragma unroll
      for (int c = 0; c < NLBL; ++c) { e[c] = expf(sm.logits[tid * NLBL + c] - mx); sum += e[c]; }
      float inv = 1.0f / sum;
#pragma unroll
      for (int c = 0; c < NLBL; ++c) out[(size_t)(gb + tid) * NLBL + c] = e[c] * inv;
    }
  }
}

extern "C" void kernel_launch(void* const* d_in, const int* in_sizes, int n_in,
                              void* d_out, int out_size, void* d_ws, size_t ws_size,
                              hipStream_t stream) {
  (void)in_sizes; (void)n_in; (void)out_size; (void)ws_size;
  const float* ts = (const float*)d_in[0];
  const float* coeffs = (const float*)d_in[1];
  const float* x0 = (const float*)d_in[2];
  const float* W1 = (const float*)d_in[3];
  const float* b1 = (const float*)d_in[4];
  const float* W2 = (const float*)d_in[5];
  const float* b2 = (const float*)d_in[6];
  const float* W3 = (const float*)d_in[7];
  const float* b3 = (const float*)d_in[8];
  const float* Wl1 = (const float*)d_in[9];
  const float* bl1 = (const float*)d_in[10];
  const float* Wl2 = (const float*)d_in[11];
  const float* bl2 = (const float*)d_in[12];

  char* ws = (char*)d_ws;
  // [0,512K): q8 fp8 W3 (dead after prologue) ALIASED with exA [0,256K) + exB [256K,512K)
  uint2* q8 = (uint2*)ws;
  float* exA = (float*)ws;
  float* exB = (float*)(ws + 262144);
  float* w3s = (float*)(ws + 524288);                  // 8KB row scales
  unsigned int* flags = (unsigned int*)(ws + 532480);  // 8KB padded counters

  static_assert(sizeof(SM) <= 160 * 1024, "LDS overflow");
  hipFuncSetAttribute(reinterpret_cast<const void*>(cde_main),
                      hipFuncAttributeMaxDynamicSharedMemorySize, (int)sizeof(SM));

  hipMemsetAsync(flags, 0, 8192, stream);
  prep_scale<<<512, 256, 0, stream>>>(W3, w3s);
  prep_pack<<<256, 256, 0, stream>>>(W3, w3s, q8);

  float* outp = (float*)d_out;
  void* args[] = {&ts, &coeffs, &x0, &b1, &b2, &b3, &Wl1, &bl1, &Wl2, &bl2,
                  &W1, &W2, &q8, &w3s, &exA, &exB, &flags, &outp};
  hipLaunchCooperativeKernel(reinterpret_cast<const void*>(cde_main), dim3(NWG), dim3(NTHR),
                             args, (unsigned int)sizeof(SM), stream);
}